// Round 6
// baseline (165.833 us; speedup 1.0000x reference)
//
#include <hip/hip_runtime.h>
#include <math.h>

// Problem constants (fixed by the reference setup_inputs): B=2, P=8192, K=16
#define PP    8192
#define NB    2
#define NPTS  16384          // NB * PP
#define KNN   16
#define EPSV  1e-17f
#define CH    128            // chunks of 64 sorted points per batch
#define NSUP  16             // super-chunks of 8 chunks (512 points)
#define NCELL 4096           // 12-bit Morton (4 bits/axis)

#define KEY_BIG 3.0e38f      // > any real key, finite

// ---------------------------------------------------------------------------
// R6: 4-queries-per-wave exact KNN, two-level bbox gate, no LDS.
// Lane (i,u): query i (0..3) = lane&3, stratum u (0..15) = lane>>2. Each
// lane keeps a PRIVATE top-16 (med3 chain) over candidates j = c*64+u+16t,
// t=0..3, of every processed chunk (disjoint, covering). Gates compare
// per-lane floor-packed dmin2(MY query, bbox) against keys[15]; process iff
// __any over the 4-query union. Two levels: 16 super-bboxes (8 chunks each)
// then chunk bboxes inside passing supers. Exactness: dmin2(super) <=
// dmin2(chunk) <= any candidate dist inside; keys only shrink; keys
// injective (idx bits) => skipped candidates provably not in the final set.
// Own chunk processed first ungated (keys start at KEY_BIG).
// Cross-lane only at the end: 4 bitonic merge16 stages across strata.
// Epilogue kernels thread-per-(q,s); pipeline stays in sorted space (loss is
// permutation-invariant); perm only gathers normals.
// ---------------------------------------------------------------------------

__device__ __forceinline__ int spread3(int v) {   // 4-bit v -> bits 0,3,6,9
    return (v & 1) | ((v & 2) << 2) | ((v & 4) << 4) | ((v & 8) << 6);
}

__global__ void hist_kernel(const float* __restrict__ pts,
                            int* __restrict__ hist) {
    const int p = blockIdx.x * blockDim.x + threadIdx.x;   // 0..16383
    const float x = pts[p * 3 + 0];
    const float y = pts[p * 3 + 1];
    const float z = pts[p * 3 + 2];
    const int ix = (int)fminf(fmaxf((x + 5.0f) * 1.6f, 0.0f), 15.0f);
    const int iy = (int)fminf(fmaxf((y + 5.0f) * 1.6f, 0.0f), 15.0f);
    const int iz = (int)fminf(fmaxf((z + 5.0f) * 1.6f, 0.0f), 15.0f);
    const int c = spread3(ix) | (spread3(iy) << 1) | (spread3(iz) << 2);
    atomicAdd(&hist[(p >> 13) * NCELL + c], 1);
}

__global__ void scan_kernel(const int* __restrict__ hist,
                            int* __restrict__ cursor) {
    // one block per batch, 1024 threads, 4 bins/thread
    const int b = blockIdx.x;
    const int t = threadIdx.x;
    const int base = b * NCELL;
    const int v0 = hist[base + t * 4 + 0];
    const int v1 = hist[base + t * 4 + 1];
    const int v2 = hist[base + t * 4 + 2];
    const int v3 = hist[base + t * 4 + 3];
    const int s4 = v0 + v1 + v2 + v3;
    const int lane = t & 63, wid = t >> 6;
    int v = s4;
#pragma unroll
    for (int off = 1; off < 64; off <<= 1) {
        int u = __shfl_up(v, off, 64);
        if (lane >= off) v += u;
    }
    __shared__ int wtot[16];
    if (lane == 63) wtot[wid] = v;
    __syncthreads();
    if (wid == 0) {
        int w = (lane < 16) ? wtot[lane] : 0;
#pragma unroll
        for (int off = 1; off < 16; off <<= 1) {
            int u = __shfl_up(w, off, 64);
            if (lane >= off) w += u;
        }
        if (lane < 16) wtot[lane] = w;          // inclusive wave totals
    }
    __syncthreads();
    const int wbase = (wid > 0) ? wtot[wid - 1] : 0;
    const int excl = wbase + v - s4;            // exclusive prefix, this thread
    const int o0 = b * PP + excl;
    cursor[base + t * 4 + 0] = o0;
    cursor[base + t * 4 + 1] = o0 + v0;
    cursor[base + t * 4 + 2] = o0 + v0 + v1;
    cursor[base + t * 4 + 3] = o0 + v0 + v1 + v2;
}

__global__ void scatter_kernel(const float* __restrict__ pts,
                               int* __restrict__ cursor,
                               float4* __restrict__ sorted4,
                               int* __restrict__ perm) {
    const int p = blockIdx.x * blockDim.x + threadIdx.x;
    const float x = pts[p * 3 + 0];
    const float y = pts[p * 3 + 1];
    const float z = pts[p * 3 + 2];
    const int ix = (int)fminf(fmaxf((x + 5.0f) * 1.6f, 0.0f), 15.0f);
    const int iy = (int)fminf(fmaxf((y + 5.0f) * 1.6f, 0.0f), 15.0f);
    const int iz = (int)fminf(fmaxf((z + 5.0f) * 1.6f, 0.0f), 15.0f);
    const int c = spread3(ix) | (spread3(iy) << 1) | (spread3(iz) << 2);
    const int pos = atomicAdd(&cursor[(p >> 13) * NCELL + c], 1);
    sorted4[pos] = make_float4(x, y, z, x * x + y * y + z * z);
    perm[pos] = p & (PP - 1);
}

// block = 512 threads = 8 waves = 8 chunks = exactly one super-chunk
__global__ void bbox_kernel(const float4* __restrict__ sorted4,
                            float4* __restrict__ bbmin,
                            float4* __restrict__ bbmax,
                            float4* __restrict__ sbmin,
                            float4* __restrict__ sbmax) {
    __shared__ float4 smn[8], smx[8];
    const int lane = threadIdx.x & 63;
    const int wave = threadIdx.x >> 6;
    const int cw = blockIdx.x * 8 + wave;       // 0..255 (abs chunk)
    const float4 v = sorted4[cw * 64 + lane];
    float mnx = v.x, mny = v.y, mnz = v.z;
    float mxx = v.x, mxy = v.y, mxz = v.z;
#pragma unroll
    for (int off = 32; off >= 1; off >>= 1) {
        mnx = fminf(mnx, __shfl_xor(mnx, off, 64));
        mny = fminf(mny, __shfl_xor(mny, off, 64));
        mnz = fminf(mnz, __shfl_xor(mnz, off, 64));
        mxx = fmaxf(mxx, __shfl_xor(mxx, off, 64));
        mxy = fmaxf(mxy, __shfl_xor(mxy, off, 64));
        mxz = fmaxf(mxz, __shfl_xor(mxz, off, 64));
    }
    if (lane == 0) {
        bbmin[cw] = make_float4(mnx, mny, mnz, 0.f);
        bbmax[cw] = make_float4(mxx, mxy, mxz, 0.f);
        smn[wave] = make_float4(mnx, mny, mnz, 0.f);
        smx[wave] = make_float4(mxx, mxy, mxz, 0.f);
    }
    __syncthreads();
    if (threadIdx.x == 0) {
        float4 a = smn[0], bmx = smx[0];
#pragma unroll
        for (int k = 1; k < 8; ++k) {
            a.x = fminf(a.x, smn[k].x); a.y = fminf(a.y, smn[k].y);
            a.z = fminf(a.z, smn[k].z);
            bmx.x = fmaxf(bmx.x, smx[k].x); bmx.y = fmaxf(bmx.y, smx[k].y);
            bmx.z = fmaxf(bmx.z, smx[k].z);
        }
        sbmin[blockIdx.x] = a;                  // blockIdx = b*16 + s
        sbmax[blockIdx.x] = bmx;
    }
}

// sorted-ascending insert of one value (private, no cross-lane)
__device__ __forceinline__ void insert16(float (&keys)[KNN], float kk) {
#pragma unroll
    for (int s = KNN - 1; s >= 1; --s)
        keys[s] = __builtin_amdgcn_fmed3f(keys[s - 1], kk, keys[s]);
    keys[0] = fminf(keys[0], kk);
}

// Merge two ascending sorted-16 lists, keep lowest 16, result ascending.
// Symmetric in (a,o): both butterfly partners produce the identical result.
__device__ __forceinline__ void merge16(float (&a)[KNN], const float (&o)[KNN]) {
    float c[KNN];
#pragma unroll
    for (int s = 0; s < KNN; ++s) c[s] = fminf(a[s], o[KNN - 1 - s]);
#pragma unroll
    for (int st = KNN / 2; st >= 1; st >>= 1) {
#pragma unroll
        for (int base = 0; base < KNN; base += 2 * st) {
#pragma unroll
            for (int k = 0; k < st; ++k) {
                const float x = c[base + k], y = c[base + k + st];
                c[base + k]      = fminf(x, y);
                c[base + k + st] = fmaxf(x, y);
            }
        }
    }
#pragma unroll
    for (int s = 0; s < KNN; ++s) a[s] = c[s];
}

// ---- K1: 4-query/wave exact KNN + phi + first denoise (fused) ---------------
__global__ __launch_bounds__(256) void knn4_kernel(
        const float4* __restrict__ sorted4,
        const int*    __restrict__ perm,
        const float*  __restrict__ normals,
        const float4* __restrict__ bbmin,
        const float4* __restrict__ bbmax,
        const float4* __restrict__ sbmin,
        const float4* __restrict__ sbmax,
        int*   __restrict__ out_idx,      // sorted-local neighbor idx
        float* __restrict__ out_phi,
        float* __restrict__ out_n1) {     // sorted-order rows
    const int lane = threadIdx.x & 63;
    const int wv   = threadIdx.x >> 6;
    const int W    = blockIdx.x * 4 + wv;        // 0..4095
    const int b    = W >> 11;                    // 2048 waves per batch
    const int qg   = W & 2047;
    const int qbase = qg * 4;                    // 4 consecutive sorted queries
    const int i    = lane & 3;                   // query within group
    const int u    = lane >> 2;                  // stratum 0..15
    const int qloc = qbase + i;                  // my query (sorted-local)
    const int c0   = qbase >> 6;                 // own chunk
    const int s0   = c0 >> 3;                    // own super
    const float4* sb = sorted4 + (size_t)b * PP;
    const int bCH = b * CH;

    const float4 q4 = sb[qloc];
    const float qx = q4.x, qy = q4.y, qz = q4.z;
    const float d2q = qx * qx + qy * qy + qz * qz;

    float keys[KNN];
#pragma unroll
    for (int s = 0; s < KNN; ++s) keys[s] = KEY_BIG;

    auto proc = [&](int c) {
#pragma unroll
        for (int t = 0; t < 4; ++t) {
            const int j = c * 64 + u + 16 * t;
            const float4 c4 = sb[j];             // 256B/wave, L2-resident
            const float dot = fmaf(qz, c4.z, fmaf(qy, c4.y, qx * c4.x));
            const float d  = fmaf(-2.0f, dot, d2q + c4.w);
            const float dc = fmaxf(d, 0.0f);
            float kv = __uint_as_float(
                (__float_as_uint(dc) & 0xFFFFE000u) | (unsigned)j);
            if (j == qloc) kv = KEY_BIG;          // exclude self
            if (__any(kv < keys[KNN - 1])) insert16(keys, kv);
        }
    };

    auto cgate = [&](int c) {
        const float4 mn = bbmin[bCH + c];         // wave-uniform -> s_load
        const float4 mx = bbmax[bCH + c];
        const float ax = fmaxf(fmaxf(mn.x - qx, qx - mx.x), 0.0f);
        const float ay = fmaxf(fmaxf(mn.y - qy, qy - mx.y), 0.0f);
        const float az = fmaxf(fmaxf(mn.z - qz, qz - mx.z), 0.0f);
        const float dm = (ax * ax + ay * ay + az * az) * 0.999999f;
        const unsigned fl = __float_as_uint(dm) & 0xFFFFE000u;
        if (__any(fl < __float_as_uint(keys[KNN - 1]))) proc(c);
    };

    auto sgate = [&](int s) {
        const float4 mn = sbmin[b * NSUP + s];
        const float4 mx = sbmax[b * NSUP + s];
        const float ax = fmaxf(fmaxf(mn.x - qx, qx - mx.x), 0.0f);
        const float ay = fmaxf(fmaxf(mn.y - qy, qy - mx.y), 0.0f);
        const float az = fmaxf(fmaxf(mn.z - qz, qz - mx.z), 0.0f);
        const float dm = (ax * ax + ay * ay + az * az) * 0.999999f;
        const unsigned fl = __float_as_uint(dm) & 0xFFFFE000u;
        if (__any(fl < __float_as_uint(keys[KNN - 1]))) {
            const int cb0 = s * 8;
            for (int k2 = 0; k2 < 8; ++k2) cgate(cb0 + k2);
        }
    };

    // own chunk first (ungated), then own super's other chunks, then supers
    proc(c0);
    {
        const int cb0 = s0 * 8;
        for (int k2 = 0; k2 < 8; ++k2) {
            const int c = cb0 + k2;
            if (c != c0) cgate(c);
        }
    }
    for (int d = 1; d < NSUP; ++d) {             // near-first super ring
        const int sp = s0 + d;
        if (sp < NSUP) sgate(sp);
        const int sm = s0 - d;
        if (sm >= 0) sgate(sm);
    }

    // ---- cross-lane: merge the 16 strata lists per query (4 stages) -------
#pragma unroll
    for (int st = 0; st < 4; ++st) {
        const int S = 4 << st;
        float o[KNN];
#pragma unroll
        for (int s = 0; s < KNN; ++s) o[s] = __shfl_xor(keys[s], S, 64);
        merge16(keys, o);
    }
    // all 16 lanes of query i now hold the identical ascending final 16

    // ---- tail: lane (i,u) finalizes slot u --------------------------------
    float myk = keys[0];
#pragma unroll
    for (int s = 1; s < KNN; ++s) myk = (u == s) ? keys[s] : myk;
    const int j = (int)(__float_as_uint(myk) & 0x1FFFu);

    const float4 nb4 = sb[j];
    const float dot = fmaf(qz, nb4.z, fmaf(qy, nb4.y, qx * nb4.x));
    float dd = fmaf(-2.0f, dot, d2q + nb4.w);
    dd = fmaxf(dd, 0.0f);

    float d1 = dd;                                // min over the 16 slots
#pragma unroll
    for (int st = 0; st < 4; ++st) d1 = fminf(d1, __shfl_xor(d1, 4 << st, 64));

    const float s0v  = d1 * 8.0f;                 // 2 * FILTER_SCALE^2 = 8
    const float sden = (s0v < EPSV) ? EPSV : s0v; // _eps_denom
    const float w  = fmaxf(1.0f - dd / sden, 0.0f);
    const float ph = (w * w) * (w * w);

    const int qrow = (b << 13) + qloc;            // sorted-order output row
    out_idx[qrow * KNN + u] = j;
    out_phi[qrow * KNN + u] = ph;

    // n1 partial (1 slot per lane), reduced across strata
    const float* bn = normals + (size_t)b * PP * 3;
    const int jo = perm[(b << 13) + j];           // original idx (normals only)
    const float nx = bn[jo * 3 + 0];
    const float ny = bn[jo * 3 + 1];
    const float nz = bn[jo * 3 + 2];
    float px = ph * nx, py = ph * ny, pz = ph * nz, ps = ph;
#pragma unroll
    for (int st = 0; st < 4; ++st) {
        const int S = 4 << st;
        px += __shfl_xor(px, S, 64);
        py += __shfl_xor(py, S, 64);
        pz += __shfl_xor(pz, S, 64);
        ps += __shfl_xor(ps, S, 64);
    }
    if (u == 0) {
        const float den = (ps < EPSV) ? EPSV : ps;
        out_n1[qrow * 3 + 0] = px / den;
        out_n1[qrow * 3 + 1] = py / den;
        out_n1[qrow * 3 + 2] = pz / den;
    }
}

// ---- K2: normal_w + second denoise (n2), thread-per-(q,s), sorted space ----
__global__ __launch_bounds__(256) void denoise2_kernel(
        const int* __restrict__ idx,
        const float* __restrict__ phi,
        const float* __restrict__ n1,
        float* __restrict__ nw_out,
        float* __restrict__ n2_out) {
    const int gid = blockIdx.x * 256 + threadIdx.x;   // 0..262143
    const int q = gid >> 4;
    const int s = gid & 15;
    const int b = q >> 13;
    const int gbase = b * PP;
    const float INV_SIG = 1.0f / (0.75f * 0.75f);

    const float ax = n1[q * 3 + 0];                   // broadcast in 16-group
    const float ay = n1[q * 3 + 1];
    const float az = n1[q * 3 + 2];
    const float an = fmaxf(sqrtf(ax * ax + ay * ay + az * az), 1e-12f);
    const float rx = ax / an, ry = ay / an, rz = az / an;

    const int j = idx[q * KNN + s];                   // sorted-local
    const float bx = n1[(gbase + j) * 3 + 0];
    const float by = n1[(gbase + j) * 3 + 1];
    const float bz = n1[(gbase + j) * 3 + 2];
    const float bnn = fmaxf(sqrtf(bx * bx + by * by + bz * bz), 1e-12f);
    const float ux = bx / bnn - rx;
    const float uy = by / bnn - ry;
    const float uz = bz / bnn - rz;
    const float dq = ux * ux + uy * uy + uz * uz;
    const float nw = expf(-dq * INV_SIG);
    nw_out[q * KNN + s] = nw;

    const float wk = phi[q * KNN + s] * nw;
    float ox = wk * bx, oy = wk * by, oz = wk * bz, swn = wk;
#pragma unroll
    for (int off = 1; off < 16; off <<= 1) {
        ox  += __shfl_xor(ox,  off, 64);
        oy  += __shfl_xor(oy,  off, 64);
        oz  += __shfl_xor(oz,  off, 64);
        swn += __shfl_xor(swn, off, 64);
    }
    if (s == 0) {
        const float den = (swn < EPSV) ? EPSV : swn;
        n2_out[q * 3 + 0] = ox / den;
        n2_out[q * 3 + 1] = oy / den;
        n2_out[q * 3 + 2] = oz / den;
    }
}

// ---- K3: weights_proj + loss, thread-per-(q,s), sorted space ----------------
__global__ __launch_bounds__(256) void loss_kernel(
        const float4* __restrict__ sorted4,
        const int* __restrict__ idx,
        const float* __restrict__ phi,
        const float* __restrict__ nw,
        const float* __restrict__ n2,
        float* __restrict__ partial) {
    const int gid = blockIdx.x * 256 + threadIdx.x;   // 0..262143
    const int q = gid >> 4;
    const int s = gid & 15;
    const int b = q >> 13;
    const int il = q & (PP - 1);
    const float4* sbp = sorted4 + (size_t)b * PP;
    const int gbase = b * PP;

    const float4 p4 = sbp[il];                        // broadcast in 16-group
    const float px = p4.x, py = p4.y, pz = p4.z;
    const float d2q = px * px + py * py + pz * pz;

    const int j = idx[q * KNN + s];
    const float4 nb4 = sbp[j];
    const float dot = fmaf(pz, nb4.z, fmaf(py, nb4.y, px * nb4.x));
    const float dv  = fmaf(-2.0f, dot, d2q + nb4.w);
    const float d   = fmaxf(dv, 0.0f);                // bit-identical to knn4

    float d1 = d;
#pragma unroll
    for (int off = 1; off < 16; off <<= 1) d1 = fminf(d1, __shfl_xor(d1, off, 64));

    float w = phi[q * KNN + s] * nw[q * KNN + s];
    if (d > 4.0f * d1) w = 0.f;                       // ball-query mask

    const float nx = n2[(gbase + j) * 3 + 0];
    const float ny = n2[(gbase + j) * 3 + 1];
    const float nz = n2[(gbase + j) * 3 + 2];
    const float dts = (nb4.x - px) * nx +
                      (nb4.y - py) * ny +
                      (nb4.z - pz) * nz;
    float num = dts * dts * w, den = w;
#pragma unroll
    for (int off = 1; off < 16; off <<= 1) {
        num += __shfl_xor(num, off, 64);
        den += __shfl_xor(den, off, 64);
    }

    __shared__ float ls[16];
    if (s == 0) {
        const float dd = (den < EPSV) ? EPSV : den;
        ls[threadIdx.x >> 4] = num / dd;
    }
    __syncthreads();
    if (threadIdx.x == 0) {
        float v = 0.f;
#pragma unroll
        for (int k = 0; k < 16; ++k) v += ls[k];
        partial[blockIdx.x] = v;
    }
}

// ---- K4: final mean (1024 partials) ----------------------------------------
__global__ void finalize_kernel(const float* __restrict__ partial,
                                float* __restrict__ out) {
    float v = 0.f;
#pragma unroll
    for (int k = 0; k < 16; ++k) v += partial[threadIdx.x + 64 * k];
#pragma unroll
    for (int off = 32; off >= 1; off >>= 1) v += __shfl_down(v, off, 64);
    if (threadIdx.x == 0) out[0] = v / (float)NPTS;
}

// ---- launch -----------------------------------------------------------------
extern "C" void kernel_launch(void* const* d_in, const int* in_sizes, int n_in,
                              void* d_out, int out_size, void* d_ws, size_t ws_size,
                              hipStream_t stream) {
    const float* points  = (const float*)d_in[0];   // (2, 8192, 3) f32
    const float* normals = (const float*)d_in[1];   // (2, 8192, 3) f32
    float* out = (float*)d_out;                     // scalar f32

    // workspace layout (floats), total 951296 < proven 1147136 budget:
    //   idx   @ 0       (262144)
    //   phi   @ 262144  (262144)
    //   nw    @ 524288  (262144)  -- doubles as sort scratch (dead after knn)
    //   n1    @ 786432  (49152)
    //   n2    @ 835584  (49152)
    //   sorted4 @ 884736 (65536)  -- float4-aligned, live through loss
    //   part  @ 950272  (1024)
    float* wsf    = (float*)d_ws;
    int*   w_idx  = (int*)wsf;
    float* w_phi  = wsf + 262144;
    float* w_nw   = wsf + 524288;
    float* w_n1   = wsf + 786432;
    float* w_n2   = wsf + 835584;
    float4* w_sorted4 = (float4*)(wsf + 884736);
    float* w_part = wsf + 950272;
    // sort scratch inside the nw region (dead once knn4 completes)
    int*    w_perm   = (int*)(wsf + 524288);        // 16384 ints
    int*    w_hist   = (int*)(wsf + 540672);        // 8192 ints
    int*    w_cursor = (int*)(wsf + 548864);        // 8192 ints
    float4* w_bbmin  = (float4*)(wsf + 557056);     // 1024 floats
    float4* w_bbmax  = (float4*)(wsf + 558080);     // 1024 floats
    float4* w_sbmin  = (float4*)(wsf + 559104);     // 128 floats
    float4* w_sbmax  = (float4*)(wsf + 559232);     // 128 floats

    hipMemsetAsync(w_hist, 0, NB * NCELL * sizeof(int), stream);
    hist_kernel   <<<NPTS / 256, 256, 0, stream>>>(points, w_hist);
    scan_kernel   <<<NB, 1024, 0, stream>>>(w_hist, w_cursor);
    scatter_kernel<<<NPTS / 256, 256, 0, stream>>>(points, w_cursor, w_sorted4, w_perm);
    bbox_kernel   <<<32, 512, 0, stream>>>(w_sorted4, w_bbmin, w_bbmax,
                                           w_sbmin, w_sbmax);
    knn4_kernel   <<<1024, 256, 0, stream>>>(w_sorted4, w_perm, normals,
                                             w_bbmin, w_bbmax, w_sbmin, w_sbmax,
                                             w_idx, w_phi, w_n1);
    denoise2_kernel<<<1024, 256, 0, stream>>>(w_idx, w_phi, w_n1, w_nw, w_n2);
    loss_kernel   <<<1024, 256, 0, stream>>>(w_sorted4, w_idx, w_phi, w_nw, w_n2, w_part);
    finalize_kernel<<<1, 64, 0, stream>>>(w_part, out);
}

// Round 7
// 160.130 us; speedup vs baseline: 1.0356x; 1.0356x over previous
//
#include <hip/hip_runtime.h>
#include <math.h>

// Problem constants (fixed by the reference setup_inputs): B=2, P=8192, K=16
#define PP    8192
#define NB    2
#define NPTS  16384          // NB * PP
#define KNN   16
#define EPSV  1e-17f
#define CH    128            // chunks of 64 sorted points per batch
#define NSUP  16             // super-chunks of 8 chunks (512 points)
#define NCELL 4096           // 12-bit Morton (4 bits/axis)

#define KEY_BIG 3.0e38f      // > any real key, finite

// ---------------------------------------------------------------------------
// R7: 4-queries-per-wave exact KNN with TIGHT merged gate bound + ballot
// batching. Lane (i,u): query i (0..3) = lane&3, stratum u (0..15) = lane>>2.
// Private per-lane top-16 (med3 chain) over candidates j = c*64+u+16t.
// NEW vs R6 (which gated on the lane-private keys[15] ~ rank-256 bound):
//  * Bq = TRUE union 16th per query (4-stage bitonic merge on a COPY of the
//    keys -> private lists preserved, no duplicate-merge bug). Refreshed
//    after the seed and after each super that processed chunks.
//  * Gates are ballot-batched: lane u holds super u's bbox; one VALU burst +
//    one __ballot yields the passing-super mask; same per 8 chunks inside a
//    passing super. No serial load->cmp->branch chain.
// Exactness: skip iff floor-pack(dmin2*0.999999) >= Bq >= current union-16th
// >= final-16th; every candidate key in the chunk >= the floor; keys
// injective (idx bits) => no final-set member skipped. Seed (own super, 512
// candidates) is processed ungated, so Bq is always a real 16th key.
// Epilogue kernels thread-per-(q,s); pipeline stays in sorted space (loss is
// permutation-invariant); perm only gathers normals.
// ---------------------------------------------------------------------------

__device__ __forceinline__ int spread3(int v) {   // 4-bit v -> bits 0,3,6,9
    return (v & 1) | ((v & 2) << 2) | ((v & 4) << 4) | ((v & 8) << 6);
}

__global__ void hist_kernel(const float* __restrict__ pts,
                            int* __restrict__ hist) {
    const int p = blockIdx.x * blockDim.x + threadIdx.x;   // 0..16383
    const float x = pts[p * 3 + 0];
    const float y = pts[p * 3 + 1];
    const float z = pts[p * 3 + 2];
    const int ix = (int)fminf(fmaxf((x + 5.0f) * 1.6f, 0.0f), 15.0f);
    const int iy = (int)fminf(fmaxf((y + 5.0f) * 1.6f, 0.0f), 15.0f);
    const int iz = (int)fminf(fmaxf((z + 5.0f) * 1.6f, 0.0f), 15.0f);
    const int c = spread3(ix) | (spread3(iy) << 1) | (spread3(iz) << 2);
    atomicAdd(&hist[(p >> 13) * NCELL + c], 1);
}

__global__ void scan_kernel(const int* __restrict__ hist,
                            int* __restrict__ cursor) {
    // one block per batch, 1024 threads, 4 bins/thread
    const int b = blockIdx.x;
    const int t = threadIdx.x;
    const int base = b * NCELL;
    const int v0 = hist[base + t * 4 + 0];
    const int v1 = hist[base + t * 4 + 1];
    const int v2 = hist[base + t * 4 + 2];
    const int v3 = hist[base + t * 4 + 3];
    const int s4 = v0 + v1 + v2 + v3;
    const int lane = t & 63, wid = t >> 6;
    int v = s4;
#pragma unroll
    for (int off = 1; off < 64; off <<= 1) {
        int u = __shfl_up(v, off, 64);
        if (lane >= off) v += u;
    }
    __shared__ int wtot[16];
    if (lane == 63) wtot[wid] = v;
    __syncthreads();
    if (wid == 0) {
        int w = (lane < 16) ? wtot[lane] : 0;
#pragma unroll
        for (int off = 1; off < 16; off <<= 1) {
            int u = __shfl_up(w, off, 64);
            if (lane >= off) w += u;
        }
        if (lane < 16) wtot[lane] = w;          // inclusive wave totals
    }
    __syncthreads();
    const int wbase = (wid > 0) ? wtot[wid - 1] : 0;
    const int excl = wbase + v - s4;            // exclusive prefix, this thread
    const int o0 = b * PP + excl;
    cursor[base + t * 4 + 0] = o0;
    cursor[base + t * 4 + 1] = o0 + v0;
    cursor[base + t * 4 + 2] = o0 + v0 + v1;
    cursor[base + t * 4 + 3] = o0 + v0 + v1 + v2;
}

__global__ void scatter_kernel(const float* __restrict__ pts,
                               int* __restrict__ cursor,
                               float4* __restrict__ sorted4,
                               int* __restrict__ perm) {
    const int p = blockIdx.x * blockDim.x + threadIdx.x;
    const float x = pts[p * 3 + 0];
    const float y = pts[p * 3 + 1];
    const float z = pts[p * 3 + 2];
    const int ix = (int)fminf(fmaxf((x + 5.0f) * 1.6f, 0.0f), 15.0f);
    const int iy = (int)fminf(fmaxf((y + 5.0f) * 1.6f, 0.0f), 15.0f);
    const int iz = (int)fminf(fmaxf((z + 5.0f) * 1.6f, 0.0f), 15.0f);
    const int c = spread3(ix) | (spread3(iy) << 1) | (spread3(iz) << 2);
    const int pos = atomicAdd(&cursor[(p >> 13) * NCELL + c], 1);
    sorted4[pos] = make_float4(x, y, z, x * x + y * y + z * z);
    perm[pos] = p & (PP - 1);
}

// block = 512 threads = 8 waves = 8 chunks = exactly one super-chunk
__global__ void bbox_kernel(const float4* __restrict__ sorted4,
                            float4* __restrict__ bbmin,
                            float4* __restrict__ bbmax,
                            float4* __restrict__ sbmin,
                            float4* __restrict__ sbmax) {
    __shared__ float4 smn[8], smx[8];
    const int lane = threadIdx.x & 63;
    const int wave = threadIdx.x >> 6;
    const int cw = blockIdx.x * 8 + wave;       // 0..255 (abs chunk)
    const float4 v = sorted4[cw * 64 + lane];
    float mnx = v.x, mny = v.y, mnz = v.z;
    float mxx = v.x, mxy = v.y, mxz = v.z;
#pragma unroll
    for (int off = 32; off >= 1; off >>= 1) {
        mnx = fminf(mnx, __shfl_xor(mnx, off, 64));
        mny = fminf(mny, __shfl_xor(mny, off, 64));
        mnz = fminf(mnz, __shfl_xor(mnz, off, 64));
        mxx = fmaxf(mxx, __shfl_xor(mxx, off, 64));
        mxy = fmaxf(mxy, __shfl_xor(mxy, off, 64));
        mxz = fmaxf(mxz, __shfl_xor(mxz, off, 64));
    }
    if (lane == 0) {
        bbmin[cw] = make_float4(mnx, mny, mnz, 0.f);
        bbmax[cw] = make_float4(mxx, mxy, mxz, 0.f);
        smn[wave] = make_float4(mnx, mny, mnz, 0.f);
        smx[wave] = make_float4(mxx, mxy, mxz, 0.f);
    }
    __syncthreads();
    if (threadIdx.x == 0) {
        float4 a = smn[0], bmx = smx[0];
#pragma unroll
        for (int k = 1; k < 8; ++k) {
            a.x = fminf(a.x, smn[k].x); a.y = fminf(a.y, smn[k].y);
            a.z = fminf(a.z, smn[k].z);
            bmx.x = fmaxf(bmx.x, smx[k].x); bmx.y = fmaxf(bmx.y, smx[k].y);
            bmx.z = fmaxf(bmx.z, smx[k].z);
        }
        sbmin[blockIdx.x] = a;                  // blockIdx = b*16 + s
        sbmax[blockIdx.x] = bmx;
    }
}

// sorted-ascending insert of one value (private, no cross-lane)
__device__ __forceinline__ void insert16(float (&keys)[KNN], float kk) {
#pragma unroll
    for (int s = KNN - 1; s >= 1; --s)
        keys[s] = __builtin_amdgcn_fmed3f(keys[s - 1], kk, keys[s]);
    keys[0] = fminf(keys[0], kk);
}

// Merge two ascending sorted-16 lists, keep lowest 16, result ascending.
// Symmetric in (a,o): both butterfly partners produce the identical result.
__device__ __forceinline__ void merge16(float (&a)[KNN], const float (&o)[KNN]) {
    float c[KNN];
#pragma unroll
    for (int s = 0; s < KNN; ++s) c[s] = fminf(a[s], o[KNN - 1 - s]);
#pragma unroll
    for (int st = KNN / 2; st >= 1; st >>= 1) {
#pragma unroll
        for (int base = 0; base < KNN; base += 2 * st) {
#pragma unroll
            for (int k = 0; k < st; ++k) {
                const float x = c[base + k], y = c[base + k + st];
                c[base + k]      = fminf(x, y);
                c[base + k + st] = fmaxf(x, y);
            }
        }
    }
#pragma unroll
    for (int s = 0; s < KNN; ++s) a[s] = c[s];
}

// ---- K1: 4-query/wave exact KNN + phi + first denoise (fused) ---------------
__global__ __launch_bounds__(256) void knn4_kernel(
        const float4* __restrict__ sorted4,
        const int*    __restrict__ perm,
        const float*  __restrict__ normals,
        const float4* __restrict__ bbmin,
        const float4* __restrict__ bbmax,
        const float4* __restrict__ sbmin,
        const float4* __restrict__ sbmax,
        int*   __restrict__ out_idx,      // sorted-local neighbor idx
        float* __restrict__ out_phi,
        float* __restrict__ out_n1) {     // sorted-order rows
    const int lane = threadIdx.x & 63;
    const int wv   = threadIdx.x >> 6;
    const int W    = blockIdx.x * 4 + wv;        // 0..4095
    const int b    = W >> 11;                    // 2048 waves per batch
    const int qg   = W & 2047;
    const int qbase = qg * 4;                    // 4 consecutive sorted queries
    const int i    = lane & 3;                   // query within group
    const int u    = lane >> 2;                  // stratum 0..15
    const int qloc = qbase + i;                  // my query (sorted-local)
    const int s0   = qbase >> 9;                 // own super (512 points)
    const float4* sb = sorted4 + (size_t)b * PP;
    const int bCH = b * CH;

    const float4 q4 = sb[qloc];
    const float qx = q4.x, qy = q4.y, qz = q4.z;
    const float d2q = qx * qx + qy * qy + qz * qz;

    // lane u holds super u's bbox (4 query-lanes share the load -> broadcast)
    const float4 smn = sbmin[b * NSUP + u];
    const float4 smx = sbmax[b * NSUP + u];

    float keys[KNN];
#pragma unroll
    for (int s = 0; s < KNN; ++s) keys[s] = KEY_BIG;

    auto proc = [&](int c) {
#pragma unroll
        for (int t = 0; t < 4; ++t) {
            const int j = c * 64 + u + 16 * t;
            const float4 c4 = sb[j];             // 256B/wave, L2-resident
            const float dot = fmaf(qz, c4.z, fmaf(qy, c4.y, qx * c4.x));
            const float d  = fmaf(-2.0f, dot, d2q + c4.w);
            const float dc = fmaxf(d, 0.0f);
            float kv = __uint_as_float(
                (__float_as_uint(dc) & 0xFFFFE000u) | (unsigned)j);
            if (j == qloc) kv = KEY_BIG;          // exclude self
            if (__any(kv < keys[KNN - 1])) insert16(keys, kv);
        }
    };

    // true union 16th for MY query (strata lanes are XOR 4/8/16/32 apart);
    // operates on a COPY so private lists stay intact (no duplicate bug).
    auto refreshB = [&]() -> unsigned {
        float tk[KNN];
#pragma unroll
        for (int s = 0; s < KNN; ++s) tk[s] = keys[s];
#pragma unroll
        for (int st = 0; st < 3; ++st) {          // XOR 4, 8, 16
            const int S = 4 << st;
            float o[KNN];
#pragma unroll
            for (int s = 0; s < KNN; ++s) o[s] = __shfl_xor(tk[s], S, 64);
            merge16(tk, o);
        }
        // value-only last stage (XOR 32): 16th of union = max of pairwise mins
        float o15[KNN];
#pragma unroll
        for (int s = 0; s < KNN; ++s) o15[s] = __shfl_xor(tk[s], 32, 64);
        float B = fminf(tk[0], o15[KNN - 1]);
#pragma unroll
        for (int s = 1; s < KNN; ++s)
            B = fmaxf(B, fminf(tk[s], o15[KNN - 1 - s]));
        return __float_as_uint(B);
    };

    // ---- seed: own super (8 chunks, ungated) ------------------------------
    const int cb0 = s0 * 8;
    for (int k = 0; k < 8; ++k) proc(cb0 + k);
    unsigned Bq = refreshB();

    // ---- ring: ballot-batched two-level gates -----------------------------
    {
        const float ax = fmaxf(fmaxf(smn.x - qx, qx - smx.x), 0.0f);
        const float ay = fmaxf(fmaxf(smn.y - qy, qy - smx.y), 0.0f);
        const float az = fmaxf(fmaxf(smn.z - qz, qz - smx.z), 0.0f);
        const float dmS = (ax * ax + ay * ay + az * az) * 0.999999f;
        const unsigned flS = __float_as_uint(dmS) & 0xFFFFE000u;
        const bool passS = (u != s0) && (flS < Bq);
        unsigned long long M = __ballot(passS);

        while (M) {
            const int bit = __ffsll(M) - 1;
            const int us = bit >> 2;              // passing super
            M &= ~(0xFULL << (us * 4));

            // 8 chunk gates in one ballot (lanes u<8 authoritative)
            const int cc = us * 8 + (u & 7);
            const float4 cmn = bbmin[bCH + cc];
            const float4 cmx = bbmax[bCH + cc];
            const float bx = fmaxf(fmaxf(cmn.x - qx, qx - cmx.x), 0.0f);
            const float by = fmaxf(fmaxf(cmn.y - qy, qy - cmx.y), 0.0f);
            const float bz = fmaxf(fmaxf(cmn.z - qz, qz - cmx.z), 0.0f);
            const float dmC = (bx * bx + by * by + bz * bz) * 0.999999f;
            const unsigned flC = __float_as_uint(dmC) & 0xFFFFE000u;
            unsigned long long M2 = __ballot(flC < Bq) & 0xFFFFFFFFull;

            const bool did = (M2 != 0);
            while (M2) {
                const int b2 = __ffsll(M2) - 1;
                const int k = b2 >> 2;            // passing chunk within super
                M2 &= ~(0xFULL << (k * 4));
                proc(us * 8 + k);
            }
            if (did && M) Bq = refreshB();        // tighten for later supers
        }
    }

    // ---- cross-lane: merge the 16 strata lists per query (4 stages) -------
#pragma unroll
    for (int st = 0; st < 4; ++st) {
        const int S = 4 << st;
        float o[KNN];
#pragma unroll
        for (int s = 0; s < KNN; ++s) o[s] = __shfl_xor(keys[s], S, 64);
        merge16(keys, o);
    }
    // all 16 lanes of query i now hold the identical ascending final 16

    // ---- tail: lane (i,u) finalizes slot u --------------------------------
    float myk = keys[0];
#pragma unroll
    for (int s = 1; s < KNN; ++s) myk = (u == s) ? keys[s] : myk;
    const int j = (int)(__float_as_uint(myk) & 0x1FFFu);

    const float4 nb4 = sb[j];
    const float dot = fmaf(qz, nb4.z, fmaf(qy, nb4.y, qx * nb4.x));
    float dd = fmaf(-2.0f, dot, d2q + nb4.w);
    dd = fmaxf(dd, 0.0f);

    float d1 = dd;                                // min over the 16 slots
#pragma unroll
    for (int st = 0; st < 4; ++st) d1 = fminf(d1, __shfl_xor(d1, 4 << st, 64));

    const float s0v  = d1 * 8.0f;                 // 2 * FILTER_SCALE^2 = 8
    const float sden = (s0v < EPSV) ? EPSV : s0v; // _eps_denom
    const float w  = fmaxf(1.0f - dd / sden, 0.0f);
    const float ph = (w * w) * (w * w);

    const int qrow = (b << 13) + qloc;            // sorted-order output row
    out_idx[qrow * KNN + u] = j;
    out_phi[qrow * KNN + u] = ph;

    // n1 partial (1 slot per lane), reduced across strata
    const float* bn = normals + (size_t)b * PP * 3;
    const int jo = perm[(b << 13) + j];           // original idx (normals only)
    const float nx = bn[jo * 3 + 0];
    const float ny = bn[jo * 3 + 1];
    const float nz = bn[jo * 3 + 2];
    float px = ph * nx, py = ph * ny, pz = ph * nz, ps = ph;
#pragma unroll
    for (int st = 0; st < 4; ++st) {
        const int S = 4 << st;
        px += __shfl_xor(px, S, 64);
        py += __shfl_xor(py, S, 64);
        pz += __shfl_xor(pz, S, 64);
        ps += __shfl_xor(ps, S, 64);
    }
    if (u == 0) {
        const float den = (ps < EPSV) ? EPSV : ps;
        out_n1[qrow * 3 + 0] = px / den;
        out_n1[qrow * 3 + 1] = py / den;
        out_n1[qrow * 3 + 2] = pz / den;
    }
}

// ---- K2: normal_w + second denoise (n2), thread-per-(q,s), sorted space ----
__global__ __launch_bounds__(256) void denoise2_kernel(
        const int* __restrict__ idx,
        const float* __restrict__ phi,
        const float* __restrict__ n1,
        float* __restrict__ nw_out,
        float* __restrict__ n2_out) {
    const int gid = blockIdx.x * 256 + threadIdx.x;   // 0..262143
    const int q = gid >> 4;
    const int s = gid & 15;
    const int b = q >> 13;
    const int gbase = b * PP;
    const float INV_SIG = 1.0f / (0.75f * 0.75f);

    const float ax = n1[q * 3 + 0];                   // broadcast in 16-group
    const float ay = n1[q * 3 + 1];
    const float az = n1[q * 3 + 2];
    const float an = fmaxf(sqrtf(ax * ax + ay * ay + az * az), 1e-12f);
    const float rx = ax / an, ry = ay / an, rz = az / an;

    const int j = idx[q * KNN + s];                   // sorted-local
    const float bx = n1[(gbase + j) * 3 + 0];
    const float by = n1[(gbase + j) * 3 + 1];
    const float bz = n1[(gbase + j) * 3 + 2];
    const float bnn = fmaxf(sqrtf(bx * bx + by * by + bz * bz), 1e-12f);
    const float ux = bx / bnn - rx;
    const float uy = by / bnn - ry;
    const float uz = bz / bnn - rz;
    const float dq = ux * ux + uy * uy + uz * uz;
    const float nw = expf(-dq * INV_SIG);
    nw_out[q * KNN + s] = nw;

    const float wk = phi[q * KNN + s] * nw;
    float ox = wk * bx, oy = wk * by, oz = wk * bz, swn = wk;
#pragma unroll
    for (int off = 1; off < 16; off <<= 1) {
        ox  += __shfl_xor(ox,  off, 64);
        oy  += __shfl_xor(oy,  off, 64);
        oz  += __shfl_xor(oz,  off, 64);
        swn += __shfl_xor(swn, off, 64);
    }
    if (s == 0) {
        const float den = (swn < EPSV) ? EPSV : swn;
        n2_out[q * 3 + 0] = ox / den;
        n2_out[q * 3 + 1] = oy / den;
        n2_out[q * 3 + 2] = oz / den;
    }
}

// ---- K3: weights_proj + loss, thread-per-(q,s), sorted space ----------------
__global__ __launch_bounds__(256) void loss_kernel(
        const float4* __restrict__ sorted4,
        const int* __restrict__ idx,
        const float* __restrict__ phi,
        const float* __restrict__ nw,
        const float* __restrict__ n2,
        float* __restrict__ partial) {
    const int gid = blockIdx.x * 256 + threadIdx.x;   // 0..262143
    const int q = gid >> 4;
    const int s = gid & 15;
    const int b = q >> 13;
    const int il = q & (PP - 1);
    const float4* sbp = sorted4 + (size_t)b * PP;
    const int gbase = b * PP;

    const float4 p4 = sbp[il];                        // broadcast in 16-group
    const float px = p4.x, py = p4.y, pz = p4.z;
    const float d2q = px * px + py * py + pz * pz;

    const int j = idx[q * KNN + s];
    const float4 nb4 = sbp[j];
    const float dot = fmaf(pz, nb4.z, fmaf(py, nb4.y, px * nb4.x));
    const float dv  = fmaf(-2.0f, dot, d2q + nb4.w);
    const float d   = fmaxf(dv, 0.0f);                // bit-identical to knn4

    float d1 = d;
#pragma unroll
    for (int off = 1; off < 16; off <<= 1) d1 = fminf(d1, __shfl_xor(d1, off, 64));

    float w = phi[q * KNN + s] * nw[q * KNN + s];
    if (d > 4.0f * d1) w = 0.f;                       // ball-query mask

    const float nx = n2[(gbase + j) * 3 + 0];
    const float ny = n2[(gbase + j) * 3 + 1];
    const float nz = n2[(gbase + j) * 3 + 2];
    const float dts = (nb4.x - px) * nx +
                      (nb4.y - py) * ny +
                      (nb4.z - pz) * nz;
    float num = dts * dts * w, den = w;
#pragma unroll
    for (int off = 1; off < 16; off <<= 1) {
        num += __shfl_xor(num, off, 64);
        den += __shfl_xor(den, off, 64);
    }

    __shared__ float ls[16];
    if (s == 0) {
        const float dd = (den < EPSV) ? EPSV : den;
        ls[threadIdx.x >> 4] = num / dd;
    }
    __syncthreads();
    if (threadIdx.x == 0) {
        float v = 0.f;
#pragma unroll
        for (int k = 0; k < 16; ++k) v += ls[k];
        partial[blockIdx.x] = v;
    }
}

// ---- K4: final mean (1024 partials) ----------------------------------------
__global__ void finalize_kernel(const float* __restrict__ partial,
                                float* __restrict__ out) {
    float v = 0.f;
#pragma unroll
    for (int k = 0; k < 16; ++k) v += partial[threadIdx.x + 64 * k];
#pragma unroll
    for (int off = 32; off >= 1; off >>= 1) v += __shfl_down(v, off, 64);
    if (threadIdx.x == 0) out[0] = v / (float)NPTS;
}

// ---- launch -----------------------------------------------------------------
extern "C" void kernel_launch(void* const* d_in, const int* in_sizes, int n_in,
                              void* d_out, int out_size, void* d_ws, size_t ws_size,
                              hipStream_t stream) {
    const float* points  = (const float*)d_in[0];   // (2, 8192, 3) f32
    const float* normals = (const float*)d_in[1];   // (2, 8192, 3) f32
    float* out = (float*)d_out;                     // scalar f32

    // workspace layout (floats), total 951296 < proven 1147136 budget:
    //   idx   @ 0       (262144)
    //   phi   @ 262144  (262144)
    //   nw    @ 524288  (262144)  -- doubles as sort scratch (dead after knn)
    //   n1    @ 786432  (49152)
    //   n2    @ 835584  (49152)
    //   sorted4 @ 884736 (65536)  -- float4-aligned, live through loss
    //   part  @ 950272  (1024)
    float* wsf    = (float*)d_ws;
    int*   w_idx  = (int*)wsf;
    float* w_phi  = wsf + 262144;
    float* w_nw   = wsf + 524288;
    float* w_n1   = wsf + 786432;
    float* w_n2   = wsf + 835584;
    float4* w_sorted4 = (float4*)(wsf + 884736);
    float* w_part = wsf + 950272;
    // sort scratch inside the nw region (dead once knn4 completes)
    int*    w_perm   = (int*)(wsf + 524288);        // 16384 ints
    int*    w_hist   = (int*)(wsf + 540672);        // 8192 ints
    int*    w_cursor = (int*)(wsf + 548864);        // 8192 ints
    float4* w_bbmin  = (float4*)(wsf + 557056);     // 1024 floats
    float4* w_bbmax  = (float4*)(wsf + 558080);     // 1024 floats
    float4* w_sbmin  = (float4*)(wsf + 559104);     // 128 floats
    float4* w_sbmax  = (float4*)(wsf + 559232);     // 128 floats

    hipMemsetAsync(w_hist, 0, NB * NCELL * sizeof(int), stream);
    hist_kernel   <<<NPTS / 256, 256, 0, stream>>>(points, w_hist);
    scan_kernel   <<<NB, 1024, 0, stream>>>(w_hist, w_cursor);
    scatter_kernel<<<NPTS / 256, 256, 0, stream>>>(points, w_cursor, w_sorted4, w_perm);
    bbox_kernel   <<<32, 512, 0, stream>>>(w_sorted4, w_bbmin, w_bbmax,
                                           w_sbmin, w_sbmax);
    knn4_kernel   <<<1024, 256, 0, stream>>>(w_sorted4, w_perm, normals,
                                             w_bbmin, w_bbmax, w_sbmin, w_sbmax,
                                             w_idx, w_phi, w_n1);
    denoise2_kernel<<<1024, 256, 0, stream>>>(w_idx, w_phi, w_n1, w_nw, w_n2);
    loss_kernel   <<<1024, 256, 0, stream>>>(w_sorted4, w_idx, w_phi, w_nw, w_n2, w_part);
    finalize_kernel<<<1, 64, 0, stream>>>(w_part, out);
}

// Round 8
// 142.728 us; speedup vs baseline: 1.1619x; 1.1219x over previous
//
#include <hip/hip_runtime.h>
#include <math.h>

// Problem constants (fixed by the reference setup_inputs): B=2, P=8192, K=16
#define PP    8192
#define NB    2
#define NPTS  16384          // NB * PP
#define KNN   16
#define EPSV  1e-17f
#define CH    128            // chunks of 64 sorted points per batch
#define NSUP  16             // super-chunks of 8 chunks (512 points)
#define NCELL 4096           // 12-bit Morton (4 bits/axis)

#define KEY_BIG 3.0e38f      // > any real key, finite

// ---------------------------------------------------------------------------
// R8: 2-queries-per-wave exact KNN at FULL occupancy (8192 waves = 32/CU),
// single post-seed bound refresh, fused single-kernel counting sort.
// Lane (i,u): query i (0..1) = lane&1, stratum u (0..31) = lane>>1. Private
// per-lane top-16 (med3 chain) over candidates j = c*64 + u + 32t, t=0..1.
// Seed: own super (8 chunks, 512 candidates) ungated. Then Bq = TRUE union
// 16th per query (4 merge stages XOR 2..16 on a COPY + value-only XOR 32),
// computed ONCE. Ring: ballot-batched super gates then chunk gates vs fixed
// Bq (order irrelevant since Bq fixed). Exactness: skip iff floor-pack
// (dmin2*0.999999) >= Bq; any candidate key in a skipped box >= floor >= Bq,
// and != Bq (keys injective, Bq is an already-collected key) => strictly
// > Bq >= final-16th => not in the final set. Cross-lane only at seed-refresh
// and the final 5-stage merge. Epilogue kernels thread-per-(q,s); pipeline
// stays in sorted space (loss permutation-invariant); perm only gathers
// normals.
// ---------------------------------------------------------------------------

__device__ __forceinline__ int spread3(int v) {   // 4-bit v -> bits 0,3,6,9
    return (v & 1) | ((v & 2) << 2) | ((v & 4) << 4) | ((v & 8) << 6);
}

// ---- S1: fused counting sort + bboxes, ONE block (1024 thr) per batch ------
__global__ __launch_bounds__(1024) void sort_kernel(
        const float* __restrict__ pts,
        float4* __restrict__ sorted4,
        int*    __restrict__ perm,
        float4* __restrict__ bbmin,
        float4* __restrict__ bbmax,
        float4* __restrict__ sbmin,
        float4* __restrict__ sbmax) {
    __shared__ int lh[NCELL];                 // 16 KB: hist -> cursors
    __shared__ int wtot[16];
    const int b = blockIdx.x;
    const int t = threadIdx.x;
    const int lane = t & 63, wid = t >> 6;
    const float* bp = pts + (size_t)b * PP * 3;

    for (int k = t; k < NCELL; k += 1024) lh[k] = 0;
    __syncthreads();

    float px[8], py[8], pz[8];
    int cell[8];
#pragma unroll
    for (int k = 0; k < 8; ++k) {
        const int p = t + k * 1024;           // coalesced
        const float x = bp[p * 3 + 0];
        const float y = bp[p * 3 + 1];
        const float z = bp[p * 3 + 2];
        px[k] = x; py[k] = y; pz[k] = z;
        const int ix = (int)fminf(fmaxf((x + 5.0f) * 1.6f, 0.0f), 15.0f);
        const int iy = (int)fminf(fmaxf((y + 5.0f) * 1.6f, 0.0f), 15.0f);
        const int iz = (int)fminf(fmaxf((z + 5.0f) * 1.6f, 0.0f), 15.0f);
        cell[k] = spread3(ix) | (spread3(iy) << 1) | (spread3(iz) << 2);
        atomicAdd(&lh[cell[k]], 1);
    }
    __syncthreads();

    // exclusive scan of lh[0..4095], 4 bins/thread (same scheme as proven R7)
    const int v0 = lh[t * 4 + 0];
    const int v1 = lh[t * 4 + 1];
    const int v2 = lh[t * 4 + 2];
    const int v3 = lh[t * 4 + 3];
    const int s4 = v0 + v1 + v2 + v3;
    int v = s4;
#pragma unroll
    for (int off = 1; off < 64; off <<= 1) {
        int uu = __shfl_up(v, off, 64);
        if (lane >= off) v += uu;
    }
    if (lane == 63) wtot[wid] = v;
    __syncthreads();
    if (wid == 0) {
        int w = (lane < 16) ? wtot[lane] : 0;
#pragma unroll
        for (int off = 1; off < 16; off <<= 1) {
            int uu = __shfl_up(w, off, 64);
            if (lane >= off) w += uu;
        }
        if (lane < 16) wtot[lane] = w;        // inclusive wave totals
    }
    __syncthreads();
    const int wbase = (wid > 0) ? wtot[wid - 1] : 0;
    const int excl = wbase + v - s4;          // exclusive prefix, this thread
    lh[t * 4 + 0] = excl;                     // own bins only: no race
    lh[t * 4 + 1] = excl + v0;
    lh[t * 4 + 2] = excl + v0 + v1;
    lh[t * 4 + 3] = excl + v0 + v1 + v2;
    __syncthreads();

#pragma unroll
    for (int k = 0; k < 8; ++k) {
        const int pos = atomicAdd(&lh[cell[k]], 1);   // local 0..8191
        sorted4[(size_t)b * PP + pos] =
            make_float4(px[k], py[k], pz[k],
                        px[k] * px[k] + py[k] * py[k] + pz[k] * pz[k]);
        perm[b * PP + pos] = t + k * 1024;    // local original index
    }
    __syncthreads();                          // block-local global writes visible

    // bboxes: wave wid handles super wid = chunks 8*wid .. 8*wid+7
    float mnsx = KEY_BIG, mnsy = KEY_BIG, mnsz = KEY_BIG;
    float mxsx = -KEY_BIG, mxsy = -KEY_BIG, mxsz = -KEY_BIG;
    for (int k = 0; k < 8; ++k) {
        const int cw = wid * 8 + k;
        const float4 vv = sorted4[(size_t)b * PP + cw * 64 + lane];
        float ax = vv.x, ay = vv.y, az = vv.z;
        float bx = vv.x, by = vv.y, bz = vv.z;
#pragma unroll
        for (int off = 32; off >= 1; off >>= 1) {
            ax = fminf(ax, __shfl_xor(ax, off, 64));
            ay = fminf(ay, __shfl_xor(ay, off, 64));
            az = fminf(az, __shfl_xor(az, off, 64));
            bx = fmaxf(bx, __shfl_xor(bx, off, 64));
            by = fmaxf(by, __shfl_xor(by, off, 64));
            bz = fmaxf(bz, __shfl_xor(bz, off, 64));
        }
        if (lane == 0) {
            bbmin[b * CH + cw] = make_float4(ax, ay, az, 0.f);
            bbmax[b * CH + cw] = make_float4(bx, by, bz, 0.f);
        }
        mnsx = fminf(mnsx, ax); mnsy = fminf(mnsy, ay); mnsz = fminf(mnsz, az);
        mxsx = fmaxf(mxsx, bx); mxsy = fmaxf(mxsy, by); mxsz = fmaxf(mxsz, bz);
    }
    if (lane == 0) {
        sbmin[b * NSUP + wid] = make_float4(mnsx, mnsy, mnsz, 0.f);
        sbmax[b * NSUP + wid] = make_float4(mxsx, mxsy, mxsz, 0.f);
    }
}

// sorted-ascending insert of one value (private, no cross-lane)
__device__ __forceinline__ void insert16(float (&keys)[KNN], float kk) {
#pragma unroll
    for (int s = KNN - 1; s >= 1; --s)
        keys[s] = __builtin_amdgcn_fmed3f(keys[s - 1], kk, keys[s]);
    keys[0] = fminf(keys[0], kk);
}

// Merge two ascending sorted-16 lists, keep lowest 16, result ascending.
// Symmetric in (a,o): both butterfly partners produce the identical result.
__device__ __forceinline__ void merge16(float (&a)[KNN], const float (&o)[KNN]) {
    float c[KNN];
#pragma unroll
    for (int s = 0; s < KNN; ++s) c[s] = fminf(a[s], o[KNN - 1 - s]);
#pragma unroll
    for (int st = KNN / 2; st >= 1; st >>= 1) {
#pragma unroll
        for (int base = 0; base < KNN; base += 2 * st) {
#pragma unroll
            for (int k = 0; k < st; ++k) {
                const float x = c[base + k], y = c[base + k + st];
                c[base + k]      = fminf(x, y);
                c[base + k + st] = fmaxf(x, y);
            }
        }
    }
#pragma unroll
    for (int s = 0; s < KNN; ++s) a[s] = c[s];
}

// ---- K1: 2-query/wave exact KNN + phi + first denoise (fused) ---------------
__global__ __launch_bounds__(256) void knn2_kernel(
        const float4* __restrict__ sorted4,
        const int*    __restrict__ perm,
        const float*  __restrict__ normals,
        const float4* __restrict__ bbmin,
        const float4* __restrict__ bbmax,
        const float4* __restrict__ sbmin,
        const float4* __restrict__ sbmax,
        int*   __restrict__ out_idx,      // sorted-local neighbor idx
        float* __restrict__ out_phi,
        float* __restrict__ out_n1) {     // sorted-order rows
    const int lane = threadIdx.x & 63;
    const int wv   = threadIdx.x >> 6;
    const int W    = blockIdx.x * 4 + wv;        // 0..8191
    const int b    = W >> 12;                    // 4096 waves per batch
    const int qg   = W & 4095;
    const int qbase = qg * 2;                    // 2 consecutive sorted queries
    const int i    = lane & 1;                   // query within pair
    const int u    = lane >> 1;                  // stratum 0..31
    const int qloc = qbase + i;                  // my query (sorted-local)
    const int s0   = qbase >> 9;                 // own super (512 points)
    const float4* sb = sorted4 + (size_t)b * PP;
    const int bCH = b * CH;

    const float4 q4 = sb[qloc];
    const float qx = q4.x, qy = q4.y, qz = q4.z;
    const float d2q = qx * qx + qy * qy + qz * qz;

    float keys[KNN];
#pragma unroll
    for (int s = 0; s < KNN; ++s) keys[s] = KEY_BIG;

    auto proc = [&](int c) {
#pragma unroll
        for (int t = 0; t < 2; ++t) {
            const int j = c * 64 + u + 32 * t;
            const float4 c4 = sb[j];             // L2-resident gather
            const float dot = fmaf(qz, c4.z, fmaf(qy, c4.y, qx * c4.x));
            const float d  = fmaf(-2.0f, dot, d2q + c4.w);
            const float dc = fmaxf(d, 0.0f);
            float kv = __uint_as_float(
                (__float_as_uint(dc) & 0xFFFFE000u) | (unsigned)j);
            if (j == qloc) kv = KEY_BIG;          // exclude self
            if (kv < keys[KNN - 1]) insert16(keys, kv);   // execz-skippable
        }
    };

    // ---- seed: own super (8 chunks, ungated) ------------------------------
    const int cb0 = s0 * 8;
    for (int k = 0; k < 8; ++k) proc(cb0 + k);

    // ---- Bq = TRUE union 16th for MY query, computed ONCE -----------------
    unsigned Bq;
    {
        float tk[KNN];
#pragma unroll
        for (int s = 0; s < KNN; ++s) tk[s] = keys[s];
#pragma unroll
        for (int st = 0; st < 4; ++st) {          // XOR 2, 4, 8, 16
            const int S = 2 << st;
            float o[KNN];
#pragma unroll
            for (int s = 0; s < KNN; ++s) o[s] = __shfl_xor(tk[s], S, 64);
            merge16(tk, o);
        }
        float o15[KNN];                           // value-only last stage
#pragma unroll
        for (int s = 0; s < KNN; ++s) o15[s] = __shfl_xor(tk[s], 32, 64);
        float B = fminf(tk[0], o15[KNN - 1]);
#pragma unroll
        for (int s = 1; s < KNN; ++s)
            B = fmaxf(B, fminf(tk[s], o15[KNN - 1 - s]));
        Bq = __float_as_uint(B);
    }

    // ---- ring: ballot-batched two-level gates vs fixed Bq -----------------
    {
        const int sup = (lane >> 2) & 15;         // 4 lanes per super (2q x2)
        const float4 smn = sbmin[b * NSUP + sup];
        const float4 smx = sbmax[b * NSUP + sup];
        const float ax = fmaxf(fmaxf(smn.x - qx, qx - smx.x), 0.0f);
        const float ay = fmaxf(fmaxf(smn.y - qy, qy - smx.y), 0.0f);
        const float az = fmaxf(fmaxf(smn.z - qz, qz - smx.z), 0.0f);
        const float dmS = (ax * ax + ay * ay + az * az) * 0.999999f;
        const unsigned flS = __float_as_uint(dmS) & 0xFFFFE000u;
        const unsigned long long M =
            __ballot((sup != s0) && (flS < Bq));

        for (int s = 0; s < NSUP; ++s) {
            if (!(M & (0xFULL << (s * 4)))) continue;
            const int cc = s * 8 + (u & 7);       // 8 lanes per chunk
            const float4 cmn = bbmin[bCH + cc];
            const float4 cmx = bbmax[bCH + cc];
            const float bx = fmaxf(fmaxf(cmn.x - qx, qx - cmx.x), 0.0f);
            const float by = fmaxf(fmaxf(cmn.y - qy, qy - cmx.y), 0.0f);
            const float bz = fmaxf(fmaxf(cmn.z - qz, qz - cmx.z), 0.0f);
            const float dmC = (bx * bx + by * by + bz * bz) * 0.999999f;
            const unsigned flC = __float_as_uint(dmC) & 0xFFFFE000u;
            const unsigned long long M2 = __ballot(flC < Bq);
#pragma unroll
            for (int k = 0; k < 8; ++k)
                if (M2 & (0x0003000300030003ULL << (2 * k))) proc(s * 8 + k);
        }
    }

    // ---- cross-lane: merge the 32 strata lists per query (5 stages) -------
#pragma unroll
    for (int st = 0; st < 5; ++st) {
        const int S = 2 << st;                    // 2,4,8,16,32 (bit0 = query)
        float o[KNN];
#pragma unroll
        for (int s = 0; s < KNN; ++s) o[s] = __shfl_xor(keys[s], S, 64);
        merge16(keys, o);
    }
    // all 32 lanes of query i now hold the identical ascending final 16

    // ---- tail: lane (i,u) handles slot u&15 (u>=16 mirrors) ---------------
    const int su = u & 15;
    float myk = keys[0];
#pragma unroll
    for (int s = 1; s < KNN; ++s) myk = (su == s) ? keys[s] : myk;
    const int j = (int)(__float_as_uint(myk) & 0x1FFFu);

    const float4 nb4 = sb[j];
    const float dot = fmaf(qz, nb4.z, fmaf(qy, nb4.y, qx * nb4.x));
    float dd = fmaf(-2.0f, dot, d2q + nb4.w);
    dd = fmaxf(dd, 0.0f);

    float d1 = dd;                                // min over the 16 slots
#pragma unroll
    for (int st = 0; st < 4; ++st) d1 = fminf(d1, __shfl_xor(d1, 2 << st, 64));

    const float s0v  = d1 * 8.0f;                 // 2 * FILTER_SCALE^2 = 8
    const float sden = (s0v < EPSV) ? EPSV : s0v; // _eps_denom
    const float w  = fmaxf(1.0f - dd / sden, 0.0f);
    const float ph = (w * w) * (w * w);

    const int qrow = (b << 13) + qloc;            // sorted-order output row
    if (u < 16) {
        out_idx[qrow * KNN + u] = j;
        out_phi[qrow * KNN + u] = ph;
    }

    // n1 partial (1 slot per lane, halves mirror), reduced across slot bits
    const float* bn = normals + (size_t)b * PP * 3;
    const int jo = perm[(b << 13) + j];           // original idx (normals only)
    const float nx = bn[jo * 3 + 0];
    const float ny = bn[jo * 3 + 1];
    const float nz = bn[jo * 3 + 2];
    float sx = ph * nx, sy = ph * ny, sz = ph * nz, ss = ph;
#pragma unroll
    for (int st = 0; st < 4; ++st) {
        const int S = 2 << st;
        sx += __shfl_xor(sx, S, 64);
        sy += __shfl_xor(sy, S, 64);
        sz += __shfl_xor(sz, S, 64);
        ss += __shfl_xor(ss, S, 64);
    }
    if (u == 0) {                                 // lanes 0 (q0) and 1 (q1)
        const float den = (ss < EPSV) ? EPSV : ss;
        out_n1[qrow * 3 + 0] = sx / den;
        out_n1[qrow * 3 + 1] = sy / den;
        out_n1[qrow * 3 + 2] = sz / den;
    }
}

// ---- K2: normal_w + second denoise (n2), thread-per-(q,s), sorted space ----
__global__ __launch_bounds__(256) void denoise2_kernel(
        const int* __restrict__ idx,
        const float* __restrict__ phi,
        const float* __restrict__ n1,
        float* __restrict__ nw_out,
        float* __restrict__ n2_out) {
    const int gid = blockIdx.x * 256 + threadIdx.x;   // 0..262143
    const int q = gid >> 4;
    const int s = gid & 15;
    const int b = q >> 13;
    const int gbase = b * PP;
    const float INV_SIG = 1.0f / (0.75f * 0.75f);

    const float ax = n1[q * 3 + 0];                   // broadcast in 16-group
    const float ay = n1[q * 3 + 1];
    const float az = n1[q * 3 + 2];
    const float an = fmaxf(sqrtf(ax * ax + ay * ay + az * az), 1e-12f);
    const float rx = ax / an, ry = ay / an, rz = az / an;

    const int j = idx[q * KNN + s];                   // sorted-local
    const float bx = n1[(gbase + j) * 3 + 0];
    const float by = n1[(gbase + j) * 3 + 1];
    const float bz = n1[(gbase + j) * 3 + 2];
    const float bnn = fmaxf(sqrtf(bx * bx + by * by + bz * bz), 1e-12f);
    const float ux = bx / bnn - rx;
    const float uy = by / bnn - ry;
    const float uz = bz / bnn - rz;
    const float dq = ux * ux + uy * uy + uz * uz;
    const float nw = expf(-dq * INV_SIG);
    nw_out[q * KNN + s] = nw;

    const float wk = phi[q * KNN + s] * nw;
    float ox = wk * bx, oy = wk * by, oz = wk * bz, swn = wk;
#pragma unroll
    for (int off = 1; off < 16; off <<= 1) {
        ox  += __shfl_xor(ox,  off, 64);
        oy  += __shfl_xor(oy,  off, 64);
        oz  += __shfl_xor(oz,  off, 64);
        swn += __shfl_xor(swn, off, 64);
    }
    if (s == 0) {
        const float den = (swn < EPSV) ? EPSV : swn;
        n2_out[q * 3 + 0] = ox / den;
        n2_out[q * 3 + 1] = oy / den;
        n2_out[q * 3 + 2] = oz / den;
    }
}

// ---- K3: weights_proj + loss, thread-per-(q,s), sorted space ----------------
__global__ __launch_bounds__(256) void loss_kernel(
        const float4* __restrict__ sorted4,
        const int* __restrict__ idx,
        const float* __restrict__ phi,
        const float* __restrict__ nw,
        const float* __restrict__ n2,
        float* __restrict__ partial) {
    const int gid = blockIdx.x * 256 + threadIdx.x;   // 0..262143
    const int q = gid >> 4;
    const int s = gid & 15;
    const int b = q >> 13;
    const int il = q & (PP - 1);
    const float4* sbp = sorted4 + (size_t)b * PP;
    const int gbase = b * PP;

    const float4 p4 = sbp[il];                        // broadcast in 16-group
    const float px = p4.x, py = p4.y, pz = p4.z;
    const float d2q = px * px + py * py + pz * pz;

    const int j = idx[q * KNN + s];
    const float4 nb4 = sbp[j];
    const float dot = fmaf(pz, nb4.z, fmaf(py, nb4.y, px * nb4.x));
    const float dv  = fmaf(-2.0f, dot, d2q + nb4.w);
    const float d   = fmaxf(dv, 0.0f);                // bit-identical to knn2

    float d1 = d;
#pragma unroll
    for (int off = 1; off < 16; off <<= 1) d1 = fminf(d1, __shfl_xor(d1, off, 64));

    float w = phi[q * KNN + s] * nw[q * KNN + s];
    if (d > 4.0f * d1) w = 0.f;                       // ball-query mask

    const float nx = n2[(gbase + j) * 3 + 0];
    const float ny = n2[(gbase + j) * 3 + 1];
    const float nz = n2[(gbase + j) * 3 + 2];
    const float dts = (nb4.x - px) * nx +
                      (nb4.y - py) * ny +
                      (nb4.z - pz) * nz;
    float num = dts * dts * w, den = w;
#pragma unroll
    for (int off = 1; off < 16; off <<= 1) {
        num += __shfl_xor(num, off, 64);
        den += __shfl_xor(den, off, 64);
    }

    __shared__ float ls[16];
    if (s == 0) {
        const float dd = (den < EPSV) ? EPSV : den;
        ls[threadIdx.x >> 4] = num / dd;
    }
    __syncthreads();
    if (threadIdx.x == 0) {
        float v = 0.f;
#pragma unroll
        for (int k = 0; k < 16; ++k) v += ls[k];
        partial[blockIdx.x] = v;
    }
}

// ---- K4: final mean (1024 partials) ----------------------------------------
__global__ void finalize_kernel(const float* __restrict__ partial,
                                float* __restrict__ out) {
    float v = 0.f;
#pragma unroll
    for (int k = 0; k < 16; ++k) v += partial[threadIdx.x + 64 * k];
#pragma unroll
    for (int off = 32; off >= 1; off >>= 1) v += __shfl_down(v, off, 64);
    if (threadIdx.x == 0) out[0] = v / (float)NPTS;
}

// ---- launch -----------------------------------------------------------------
extern "C" void kernel_launch(void* const* d_in, const int* in_sizes, int n_in,
                              void* d_out, int out_size, void* d_ws, size_t ws_size,
                              hipStream_t stream) {
    const float* points  = (const float*)d_in[0];   // (2, 8192, 3) f32
    const float* normals = (const float*)d_in[1];   // (2, 8192, 3) f32
    float* out = (float*)d_out;                     // scalar f32

    // workspace layout (floats), total 951296 < proven 1147136 budget:
    //   idx   @ 0       (262144)
    //   phi   @ 262144  (262144)
    //   nw    @ 524288  (262144)  -- doubles as sort scratch (dead after knn)
    //   n1    @ 786432  (49152)
    //   n2    @ 835584  (49152)
    //   sorted4 @ 884736 (65536)  -- float4-aligned, live through loss
    //   part  @ 950272  (1024)
    float* wsf    = (float*)d_ws;
    int*   w_idx  = (int*)wsf;
    float* w_phi  = wsf + 262144;
    float* w_nw   = wsf + 524288;
    float* w_n1   = wsf + 786432;
    float* w_n2   = wsf + 835584;
    float4* w_sorted4 = (float4*)(wsf + 884736);
    float* w_part = wsf + 950272;
    // sort scratch inside the nw region (dead once knn2 completes)
    int*    w_perm   = (int*)(wsf + 524288);        // 16384 ints
    float4* w_bbmin  = (float4*)(wsf + 557056);     // 1024 floats
    float4* w_bbmax  = (float4*)(wsf + 558080);     // 1024 floats
    float4* w_sbmin  = (float4*)(wsf + 559104);     // 128 floats
    float4* w_sbmax  = (float4*)(wsf + 559232);     // 128 floats

    sort_kernel   <<<NB, 1024, 0, stream>>>(points, w_sorted4, w_perm,
                                            w_bbmin, w_bbmax, w_sbmin, w_sbmax);
    knn2_kernel   <<<2048, 256, 0, stream>>>(w_sorted4, w_perm, normals,
                                             w_bbmin, w_bbmax, w_sbmin, w_sbmax,
                                             w_idx, w_phi, w_n1);
    denoise2_kernel<<<1024, 256, 0, stream>>>(w_idx, w_phi, w_n1, w_nw, w_n2);
    loss_kernel   <<<1024, 256, 0, stream>>>(w_sorted4, w_idx, w_phi, w_nw, w_n2, w_part);
    finalize_kernel<<<1, 64, 0, stream>>>(w_part, out);
}

// Round 9
// 133.566 us; speedup vs baseline: 1.2416x; 1.0686x over previous
//
#include <hip/hip_runtime.h>
#include <math.h>

// Problem constants (fixed by the reference setup_inputs): B=2, P=8192, K=16
#define PP    8192
#define NB    2
#define NPTS  16384          // NB * PP
#define KNN   16
#define EPSV  1e-17f
#define CH    128            // chunks of 64 sorted points per batch
#define NSUP  16             // super-chunks of 8 chunks (512 points)
#define NCELL 4096           // 12-bit Morton (4 bits/axis)

#define KEY_BIG 3.0e38f      // > any real key, finite

// ---------------------------------------------------------------------------
// R9 = R8 with the prologue regression fixed:
//  * sort_kernel (2 blocks) keeps ONLY hist -> scan -> scatter (sequential by
//    nature, cheap, LDS hist avoids a memset dispatch).
//  * bbox computation moved back to a 32-block kernel (R7-proven): the
//    dependent shfl-reduction work runs on 32 CUs instead of 2.
// knn2 (61 us, proven exact) and the epilogue are byte-identical to R8.
// Exactness (unchanged): private per-lane top-16 over strata j=c*64+u+32t;
// seed = own super ungated; Bq = true union 16th (merge on a COPY), fixed;
// skip iff floor-pack(dmin2*0.999999) >= Bq; keys injective => skipped
// candidates provably outside the final set.
// ---------------------------------------------------------------------------

__device__ __forceinline__ int spread3(int v) {   // 4-bit v -> bits 0,3,6,9
    return (v & 1) | ((v & 2) << 2) | ((v & 4) << 4) | ((v & 8) << 6);
}

// ---- S1: fused counting sort (hist+scan+scatter), ONE block per batch ------
__global__ __launch_bounds__(1024) void sort_kernel(
        const float* __restrict__ pts,
        float4* __restrict__ sorted4,
        int*    __restrict__ perm) {
    __shared__ int lh[NCELL];                 // 16 KB: hist -> cursors
    __shared__ int wtot[16];
    const int b = blockIdx.x;
    const int t = threadIdx.x;
    const int lane = t & 63, wid = t >> 6;
    const float* bp = pts + (size_t)b * PP * 3;

    for (int k = t; k < NCELL; k += 1024) lh[k] = 0;
    __syncthreads();

    float px[8], py[8], pz[8];
    int cell[8];
#pragma unroll
    for (int k = 0; k < 8; ++k) {
        const int p = t + k * 1024;           // coalesced
        const float x = bp[p * 3 + 0];
        const float y = bp[p * 3 + 1];
        const float z = bp[p * 3 + 2];
        px[k] = x; py[k] = y; pz[k] = z;
        const int ix = (int)fminf(fmaxf((x + 5.0f) * 1.6f, 0.0f), 15.0f);
        const int iy = (int)fminf(fmaxf((y + 5.0f) * 1.6f, 0.0f), 15.0f);
        const int iz = (int)fminf(fmaxf((z + 5.0f) * 1.6f, 0.0f), 15.0f);
        cell[k] = spread3(ix) | (spread3(iy) << 1) | (spread3(iz) << 2);
        atomicAdd(&lh[cell[k]], 1);
    }
    __syncthreads();

    // exclusive scan of lh[0..4095], 4 bins/thread (proven R7/R8 scheme)
    const int v0 = lh[t * 4 + 0];
    const int v1 = lh[t * 4 + 1];
    const int v2 = lh[t * 4 + 2];
    const int v3 = lh[t * 4 + 3];
    const int s4 = v0 + v1 + v2 + v3;
    int v = s4;
#pragma unroll
    for (int off = 1; off < 64; off <<= 1) {
        int uu = __shfl_up(v, off, 64);
        if (lane >= off) v += uu;
    }
    if (lane == 63) wtot[wid] = v;
    __syncthreads();
    if (wid == 0) {
        int w = (lane < 16) ? wtot[lane] : 0;
#pragma unroll
        for (int off = 1; off < 16; off <<= 1) {
            int uu = __shfl_up(w, off, 64);
            if (lane >= off) w += uu;
        }
        if (lane < 16) wtot[lane] = w;        // inclusive wave totals
    }
    __syncthreads();
    const int wbase = (wid > 0) ? wtot[wid - 1] : 0;
    const int excl = wbase + v - s4;          // exclusive prefix, this thread
    lh[t * 4 + 0] = excl;                     // own bins only: no race
    lh[t * 4 + 1] = excl + v0;
    lh[t * 4 + 2] = excl + v0 + v1;
    lh[t * 4 + 3] = excl + v0 + v1 + v2;
    __syncthreads();

#pragma unroll
    for (int k = 0; k < 8; ++k) {
        const int pos = atomicAdd(&lh[cell[k]], 1);   // local 0..8191
        sorted4[(size_t)b * PP + pos] =
            make_float4(px[k], py[k], pz[k],
                        px[k] * px[k] + py[k] * py[k] + pz[k] * pz[k]);
        perm[b * PP + pos] = t + k * 1024;    // local original index
    }
}

// ---- S2: chunk + super bboxes, block = 8 waves = one super (32 blocks) -----
__global__ void bbox_kernel(const float4* __restrict__ sorted4,
                            float4* __restrict__ bbmin,
                            float4* __restrict__ bbmax,
                            float4* __restrict__ sbmin,
                            float4* __restrict__ sbmax) {
    __shared__ float4 smn[8], smx[8];
    const int lane = threadIdx.x & 63;
    const int wave = threadIdx.x >> 6;
    const int cw = blockIdx.x * 8 + wave;       // 0..255 (abs chunk)
    const float4 v = sorted4[cw * 64 + lane];
    float mnx = v.x, mny = v.y, mnz = v.z;
    float mxx = v.x, mxy = v.y, mxz = v.z;
#pragma unroll
    for (int off = 32; off >= 1; off >>= 1) {
        mnx = fminf(mnx, __shfl_xor(mnx, off, 64));
        mny = fminf(mny, __shfl_xor(mny, off, 64));
        mnz = fminf(mnz, __shfl_xor(mnz, off, 64));
        mxx = fmaxf(mxx, __shfl_xor(mxx, off, 64));
        mxy = fmaxf(mxy, __shfl_xor(mxy, off, 64));
        mxz = fmaxf(mxz, __shfl_xor(mxz, off, 64));
    }
    if (lane == 0) {
        bbmin[cw] = make_float4(mnx, mny, mnz, 0.f);
        bbmax[cw] = make_float4(mxx, mxy, mxz, 0.f);
        smn[wave] = make_float4(mnx, mny, mnz, 0.f);
        smx[wave] = make_float4(mxx, mxy, mxz, 0.f);
    }
    __syncthreads();
    if (threadIdx.x == 0) {
        float4 a = smn[0], bmx = smx[0];
#pragma unroll
        for (int k = 1; k < 8; ++k) {
            a.x = fminf(a.x, smn[k].x); a.y = fminf(a.y, smn[k].y);
            a.z = fminf(a.z, smn[k].z);
            bmx.x = fmaxf(bmx.x, smx[k].x); bmx.y = fmaxf(bmx.y, smx[k].y);
            bmx.z = fmaxf(bmx.z, smx[k].z);
        }
        sbmin[blockIdx.x] = a;                  // blockIdx = b*16 + s
        sbmax[blockIdx.x] = bmx;
    }
}

// sorted-ascending insert of one value (private, no cross-lane)
__device__ __forceinline__ void insert16(float (&keys)[KNN], float kk) {
#pragma unroll
    for (int s = KNN - 1; s >= 1; --s)
        keys[s] = __builtin_amdgcn_fmed3f(keys[s - 1], kk, keys[s]);
    keys[0] = fminf(keys[0], kk);
}

// Merge two ascending sorted-16 lists, keep lowest 16, result ascending.
// Symmetric in (a,o): both butterfly partners produce the identical result.
__device__ __forceinline__ void merge16(float (&a)[KNN], const float (&o)[KNN]) {
    float c[KNN];
#pragma unroll
    for (int s = 0; s < KNN; ++s) c[s] = fminf(a[s], o[KNN - 1 - s]);
#pragma unroll
    for (int st = KNN / 2; st >= 1; st >>= 1) {
#pragma unroll
        for (int base = 0; base < KNN; base += 2 * st) {
#pragma unroll
            for (int k = 0; k < st; ++k) {
                const float x = c[base + k], y = c[base + k + st];
                c[base + k]      = fminf(x, y);
                c[base + k + st] = fmaxf(x, y);
            }
        }
    }
#pragma unroll
    for (int s = 0; s < KNN; ++s) a[s] = c[s];
}

// ---- K1: 2-query/wave exact KNN + phi + first denoise (fused) ---------------
__global__ __launch_bounds__(256) void knn2_kernel(
        const float4* __restrict__ sorted4,
        const int*    __restrict__ perm,
        const float*  __restrict__ normals,
        const float4* __restrict__ bbmin,
        const float4* __restrict__ bbmax,
        const float4* __restrict__ sbmin,
        const float4* __restrict__ sbmax,
        int*   __restrict__ out_idx,      // sorted-local neighbor idx
        float* __restrict__ out_phi,
        float* __restrict__ out_n1) {     // sorted-order rows
    const int lane = threadIdx.x & 63;
    const int wv   = threadIdx.x >> 6;
    const int W    = blockIdx.x * 4 + wv;        // 0..8191
    const int b    = W >> 12;                    // 4096 waves per batch
    const int qg   = W & 4095;
    const int qbase = qg * 2;                    // 2 consecutive sorted queries
    const int i    = lane & 1;                   // query within pair
    const int u    = lane >> 1;                  // stratum 0..31
    const int qloc = qbase + i;                  // my query (sorted-local)
    const int s0   = qbase >> 9;                 // own super (512 points)
    const float4* sb = sorted4 + (size_t)b * PP;
    const int bCH = b * CH;

    const float4 q4 = sb[qloc];
    const float qx = q4.x, qy = q4.y, qz = q4.z;
    const float d2q = qx * qx + qy * qy + qz * qz;

    float keys[KNN];
#pragma unroll
    for (int s = 0; s < KNN; ++s) keys[s] = KEY_BIG;

    auto proc = [&](int c) {
#pragma unroll
        for (int t = 0; t < 2; ++t) {
            const int j = c * 64 + u + 32 * t;
            const float4 c4 = sb[j];             // L2-resident gather
            const float dot = fmaf(qz, c4.z, fmaf(qy, c4.y, qx * c4.x));
            const float d  = fmaf(-2.0f, dot, d2q + c4.w);
            const float dc = fmaxf(d, 0.0f);
            float kv = __uint_as_float(
                (__float_as_uint(dc) & 0xFFFFE000u) | (unsigned)j);
            if (j == qloc) kv = KEY_BIG;          // exclude self
            if (kv < keys[KNN - 1]) insert16(keys, kv);   // execz-skippable
        }
    };

    // ---- seed: own super (8 chunks, ungated) ------------------------------
    const int cb0 = s0 * 8;
    for (int k = 0; k < 8; ++k) proc(cb0 + k);

    // ---- Bq = TRUE union 16th for MY query, computed ONCE -----------------
    unsigned Bq;
    {
        float tk[KNN];
#pragma unroll
        for (int s = 0; s < KNN; ++s) tk[s] = keys[s];
#pragma unroll
        for (int st = 0; st < 4; ++st) {          // XOR 2, 4, 8, 16
            const int S = 2 << st;
            float o[KNN];
#pragma unroll
            for (int s = 0; s < KNN; ++s) o[s] = __shfl_xor(tk[s], S, 64);
            merge16(tk, o);
        }
        float o15[KNN];                           // value-only last stage
#pragma unroll
        for (int s = 0; s < KNN; ++s) o15[s] = __shfl_xor(tk[s], 32, 64);
        float B = fminf(tk[0], o15[KNN - 1]);
#pragma unroll
        for (int s = 1; s < KNN; ++s)
            B = fmaxf(B, fminf(tk[s], o15[KNN - 1 - s]));
        Bq = __float_as_uint(B);
    }

    // ---- ring: ballot-batched two-level gates vs fixed Bq -----------------
    {
        const int sup = (lane >> 2) & 15;         // 4 lanes per super (2q x2)
        const float4 smn = sbmin[b * NSUP + sup];
        const float4 smx = sbmax[b * NSUP + sup];
        const float ax = fmaxf(fmaxf(smn.x - qx, qx - smx.x), 0.0f);
        const float ay = fmaxf(fmaxf(smn.y - qy, qy - smx.y), 0.0f);
        const float az = fmaxf(fmaxf(smn.z - qz, qz - smx.z), 0.0f);
        const float dmS = (ax * ax + ay * ay + az * az) * 0.999999f;
        const unsigned flS = __float_as_uint(dmS) & 0xFFFFE000u;
        const unsigned long long M =
            __ballot((sup != s0) && (flS < Bq));

        for (int s = 0; s < NSUP; ++s) {
            if (!(M & (0xFULL << (s * 4)))) continue;
            const int cc = s * 8 + (u & 7);       // 8 lanes per chunk
            const float4 cmn = bbmin[bCH + cc];
            const float4 cmx = bbmax[bCH + cc];
            const float bx = fmaxf(fmaxf(cmn.x - qx, qx - cmx.x), 0.0f);
            const float by = fmaxf(fmaxf(cmn.y - qy, qy - cmx.y), 0.0f);
            const float bz = fmaxf(fmaxf(cmn.z - qz, qz - cmx.z), 0.0f);
            const float dmC = (bx * bx + by * by + bz * bz) * 0.999999f;
            const unsigned flC = __float_as_uint(dmC) & 0xFFFFE000u;
            const unsigned long long M2 = __ballot(flC < Bq);
#pragma unroll
            for (int k = 0; k < 8; ++k)
                if (M2 & (0x0003000300030003ULL << (2 * k))) proc(s * 8 + k);
        }
    }

    // ---- cross-lane: merge the 32 strata lists per query (5 stages) -------
#pragma unroll
    for (int st = 0; st < 5; ++st) {
        const int S = 2 << st;                    // 2,4,8,16,32 (bit0 = query)
        float o[KNN];
#pragma unroll
        for (int s = 0; s < KNN; ++s) o[s] = __shfl_xor(keys[s], S, 64);
        merge16(keys, o);
    }
    // all 32 lanes of query i now hold the identical ascending final 16

    // ---- tail: lane (i,u) handles slot u&15 (u>=16 mirrors) ---------------
    const int su = u & 15;
    float myk = keys[0];
#pragma unroll
    for (int s = 1; s < KNN; ++s) myk = (su == s) ? keys[s] : myk;
    const int j = (int)(__float_as_uint(myk) & 0x1FFFu);

    const float4 nb4 = sb[j];
    const float dot = fmaf(qz, nb4.z, fmaf(qy, nb4.y, qx * nb4.x));
    float dd = fmaf(-2.0f, dot, d2q + nb4.w);
    dd = fmaxf(dd, 0.0f);

    float d1 = dd;                                // min over the 16 slots
#pragma unroll
    for (int st = 0; st < 4; ++st) d1 = fminf(d1, __shfl_xor(d1, 2 << st, 64));

    const float s0v  = d1 * 8.0f;                 // 2 * FILTER_SCALE^2 = 8
    const float sden = (s0v < EPSV) ? EPSV : s0v; // _eps_denom
    const float w  = fmaxf(1.0f - dd / sden, 0.0f);
    const float ph = (w * w) * (w * w);

    const int qrow = (b << 13) + qloc;            // sorted-order output row
    if (u < 16) {
        out_idx[qrow * KNN + u] = j;
        out_phi[qrow * KNN + u] = ph;
    }

    // n1 partial (1 slot per lane, halves mirror), reduced across slot bits
    const float* bn = normals + (size_t)b * PP * 3;
    const int jo = perm[(b << 13) + j];           // original idx (normals only)
    const float nx = bn[jo * 3 + 0];
    const float ny = bn[jo * 3 + 1];
    const float nz = bn[jo * 3 + 2];
    float sx = ph * nx, sy = ph * ny, sz = ph * nz, ss = ph;
#pragma unroll
    for (int st = 0; st < 4; ++st) {
        const int S = 2 << st;
        sx += __shfl_xor(sx, S, 64);
        sy += __shfl_xor(sy, S, 64);
        sz += __shfl_xor(sz, S, 64);
        ss += __shfl_xor(ss, S, 64);
    }
    if (u == 0) {                                 // lanes 0 (q0) and 1 (q1)
        const float den = (ss < EPSV) ? EPSV : ss;
        out_n1[qrow * 3 + 0] = sx / den;
        out_n1[qrow * 3 + 1] = sy / den;
        out_n1[qrow * 3 + 2] = sz / den;
    }
}

// ---- K2: normal_w + second denoise (n2), thread-per-(q,s), sorted space ----
__global__ __launch_bounds__(256) void denoise2_kernel(
        const int* __restrict__ idx,
        const float* __restrict__ phi,
        const float* __restrict__ n1,
        float* __restrict__ nw_out,
        float* __restrict__ n2_out) {
    const int gid = blockIdx.x * 256 + threadIdx.x;   // 0..262143
    const int q = gid >> 4;
    const int s = gid & 15;
    const int b = q >> 13;
    const int gbase = b * PP;
    const float INV_SIG = 1.0f / (0.75f * 0.75f);

    const float ax = n1[q * 3 + 0];                   // broadcast in 16-group
    const float ay = n1[q * 3 + 1];
    const float az = n1[q * 3 + 2];
    const float an = fmaxf(sqrtf(ax * ax + ay * ay + az * az), 1e-12f);
    const float rx = ax / an, ry = ay / an, rz = az / an;

    const int j = idx[q * KNN + s];                   // sorted-local
    const float bx = n1[(gbase + j) * 3 + 0];
    const float by = n1[(gbase + j) * 3 + 1];
    const float bz = n1[(gbase + j) * 3 + 2];
    const float bnn = fmaxf(sqrtf(bx * bx + by * by + bz * bz), 1e-12f);
    const float ux = bx / bnn - rx;
    const float uy = by / bnn - ry;
    const float uz = bz / bnn - rz;
    const float dq = ux * ux + uy * uy + uz * uz;
    const float nw = expf(-dq * INV_SIG);
    nw_out[q * KNN + s] = nw;

    const float wk = phi[q * KNN + s] * nw;
    float ox = wk * bx, oy = wk * by, oz = wk * bz, swn = wk;
#pragma unroll
    for (int off = 1; off < 16; off <<= 1) {
        ox  += __shfl_xor(ox,  off, 64);
        oy  += __shfl_xor(oy,  off, 64);
        oz  += __shfl_xor(oz,  off, 64);
        swn += __shfl_xor(swn, off, 64);
    }
    if (s == 0) {
        const float den = (swn < EPSV) ? EPSV : swn;
        n2_out[q * 3 + 0] = ox / den;
        n2_out[q * 3 + 1] = oy / den;
        n2_out[q * 3 + 2] = oz / den;
    }
}

// ---- K3: weights_proj + loss, thread-per-(q,s), sorted space ----------------
__global__ __launch_bounds__(256) void loss_kernel(
        const float4* __restrict__ sorted4,
        const int* __restrict__ idx,
        const float* __restrict__ phi,
        const float* __restrict__ nw,
        const float* __restrict__ n2,
        float* __restrict__ partial) {
    const int gid = blockIdx.x * 256 + threadIdx.x;   // 0..262143
    const int q = gid >> 4;
    const int s = gid & 15;
    const int b = q >> 13;
    const int il = q & (PP - 1);
    const float4* sbp = sorted4 + (size_t)b * PP;
    const int gbase = b * PP;

    const float4 p4 = sbp[il];                        // broadcast in 16-group
    const float px = p4.x, py = p4.y, pz = p4.z;
    const float d2q = px * px + py * py + pz * pz;

    const int j = idx[q * KNN + s];
    const float4 nb4 = sbp[j];
    const float dot = fmaf(pz, nb4.z, fmaf(py, nb4.y, px * nb4.x));
    const float dv  = fmaf(-2.0f, dot, d2q + nb4.w);
    const float d   = fmaxf(dv, 0.0f);                // bit-identical to knn2

    float d1 = d;
#pragma unroll
    for (int off = 1; off < 16; off <<= 1) d1 = fminf(d1, __shfl_xor(d1, off, 64));

    float w = phi[q * KNN + s] * nw[q * KNN + s];
    if (d > 4.0f * d1) w = 0.f;                       // ball-query mask

    const float nx = n2[(gbase + j) * 3 + 0];
    const float ny = n2[(gbase + j) * 3 + 1];
    const float nz = n2[(gbase + j) * 3 + 2];
    const float dts = (nb4.x - px) * nx +
                      (nb4.y - py) * ny +
                      (nb4.z - pz) * nz;
    float num = dts * dts * w, den = w;
#pragma unroll
    for (int off = 1; off < 16; off <<= 1) {
        num += __shfl_xor(num, off, 64);
        den += __shfl_xor(den, off, 64);
    }

    __shared__ float ls[16];
    if (s == 0) {
        const float dd = (den < EPSV) ? EPSV : den;
        ls[threadIdx.x >> 4] = num / dd;
    }
    __syncthreads();
    if (threadIdx.x == 0) {
        float v = 0.f;
#pragma unroll
        for (int k = 0; k < 16; ++k) v += ls[k];
        partial[blockIdx.x] = v;
    }
}

// ---- K4: final mean (1024 partials) ----------------------------------------
__global__ void finalize_kernel(const float* __restrict__ partial,
                                float* __restrict__ out) {
    float v = 0.f;
#pragma unroll
    for (int k = 0; k < 16; ++k) v += partial[threadIdx.x + 64 * k];
#pragma unroll
    for (int off = 32; off >= 1; off >>= 1) v += __shfl_down(v, off, 64);
    if (threadIdx.x == 0) out[0] = v / (float)NPTS;
}

// ---- launch -----------------------------------------------------------------
extern "C" void kernel_launch(void* const* d_in, const int* in_sizes, int n_in,
                              void* d_out, int out_size, void* d_ws, size_t ws_size,
                              hipStream_t stream) {
    const float* points  = (const float*)d_in[0];   // (2, 8192, 3) f32
    const float* normals = (const float*)d_in[1];   // (2, 8192, 3) f32
    float* out = (float*)d_out;                     // scalar f32

    // workspace layout (floats), total 951296 < proven 1147136 budget:
    //   idx   @ 0       (262144)
    //   phi   @ 262144  (262144)
    //   nw    @ 524288  (262144)  -- doubles as sort scratch (dead after knn)
    //   n1    @ 786432  (49152)
    //   n2    @ 835584  (49152)
    //   sorted4 @ 884736 (65536)  -- float4-aligned, live through loss
    //   part  @ 950272  (1024)
    float* wsf    = (float*)d_ws;
    int*   w_idx  = (int*)wsf;
    float* w_phi  = wsf + 262144;
    float* w_nw   = wsf + 524288;
    float* w_n1   = wsf + 786432;
    float* w_n2   = wsf + 835584;
    float4* w_sorted4 = (float4*)(wsf + 884736);
    float* w_part = wsf + 950272;
    // sort scratch inside the nw region (dead once knn2 completes)
    int*    w_perm   = (int*)(wsf + 524288);        // 16384 ints
    float4* w_bbmin  = (float4*)(wsf + 557056);     // 1024 floats
    float4* w_bbmax  = (float4*)(wsf + 558080);     // 1024 floats
    float4* w_sbmin  = (float4*)(wsf + 559104);     // 128 floats
    float4* w_sbmax  = (float4*)(wsf + 559232);     // 128 floats

    sort_kernel   <<<NB, 1024, 0, stream>>>(points, w_sorted4, w_perm);
    bbox_kernel   <<<32, 512, 0, stream>>>(w_sorted4, w_bbmin, w_bbmax,
                                           w_sbmin, w_sbmax);
    knn2_kernel   <<<2048, 256, 0, stream>>>(w_sorted4, w_perm, normals,
                                             w_bbmin, w_bbmax, w_sbmin, w_sbmax,
                                             w_idx, w_phi, w_n1);
    denoise2_kernel<<<1024, 256, 0, stream>>>(w_idx, w_phi, w_n1, w_nw, w_n2);
    loss_kernel   <<<1024, 256, 0, stream>>>(w_sorted4, w_idx, w_phi, w_nw, w_n2, w_part);
    finalize_kernel<<<1, 64, 0, stream>>>(w_part, out);
}